// Round 1
// 213.997 us; speedup vs baseline: 1.0385x; 1.0385x over previous
//
#include <hip/hip_runtime.h>
#include <cstdint>
#include <cstddef>

// One wave (64 lanes) per batch (B=4096, N=K=64).
// R7 change vs R6 (verified 143 us dispatch): replace the v_readlane+v_mov
// broadcast plumbing in the sinkhorn loop (64 readlane + ~32 mov per phase to
// feed 16 pk_fma) with an LDS broadcast buffer: 1 ds_write_b32 + 16
// wave-uniform-address ds_read_b128 per phase. Same-address LDS reads are a
// hardware broadcast (no bank conflict); DS ops from one wave execute in
// order, so no barrier is needed in a 1-wave workgroup. The float4 reads give
// exactly the (4t,4t+1),(4t+2,4t+3) pairing of R4/R6, fed to the identical
// fma2 sequence and identical reduction/divide order => bitwise-identical
// sinkhorn scores. Greedy phase is R5 verbatim.

typedef float f2 __attribute__((ext_vector_type(2)));

__device__ __forceinline__ f2 fma2(f2 a, f2 b, f2 c) {
#if defined(__has_builtin) && __has_builtin(__builtin_elementwise_fma)
    return __builtin_elementwise_fma(a, b, c);
#else
    f2 r; r.x = __builtin_fmaf(a.x, b.x, c.x); r.y = __builtin_fmaf(a.y, b.y, c.y);
    return r;
#endif
}

#define RESCAN(G)                                                            \
  {                                                                          \
    float nv_ = -__builtin_inff(); int na_ = (G) * 8;                        \
    _Pragma("unroll")                                                        \
    for (int k_ = 0; k_ < 8; ++k_) {                                         \
      const int idx_ = (G) * 8 + k_;                                         \
      float vk_ = ((rowmask >> idx_) & 1ull) ? col[idx_]                     \
                                             : -__builtin_inff();            \
      if (vk_ > nv_) { nv_ = vk_; na_ = idx_; }                              \
    }                                                                        \
    gv[(G)] = nv_; ga[(G)] = na_;                                            \
  }

#define RESCAN_SWITCH(RG)                                                    \
    switch (RG) {                                                            \
        case 0: RESCAN(0) break;                                             \
        case 1: RESCAN(1) break;                                             \
        case 2: RESCAN(2) break;                                             \
        case 3: RESCAN(3) break;                                             \
        case 4: RESCAN(4) break;                                             \
        case 5: RESCAN(5) break;                                             \
        case 6: RESCAN(6) break;                                             \
        case 7: RESCAN(7) break;                                             \
    }

__global__ void __launch_bounds__(64)
__attribute__((amdgpu_waves_per_eu(1)))
sinkhorn_perm_kernel(const float* __restrict__ logits,
                     const float* __restrict__ ptemp,
                     float* __restrict__ out)
{
    __shared__ __attribute__((aligned(16))) float bufU[64];
    __shared__ __attribute__((aligned(16))) float bufV[64];

    const int b    = blockIdx.x;
    const int lane = threadIdx.x;
    const float* base = logits + (size_t)b * 4096;

    const float T    = ptemp[0] + 1e-6f;
    const float invT = 1.0f / T;          // IEEE divide (one-time)

    // ---- load row `lane`, scale by invT; pairs (4t,4t+1),(4t+2,4t+3) --
    f2 row2[32];
    {
        const float4* rp = (const float4*)(base + lane * 64);
        #pragma unroll
        for (int t = 0; t < 16; ++t) {
            float4 q = rp[t];
            row2[2*t+0].x = __fmul_rn(q.x, invT);
            row2[2*t+0].y = __fmul_rn(q.y, invT);
            row2[2*t+1].x = __fmul_rn(q.z, invT);
            row2[2*t+1].y = __fmul_rn(q.w, invT);
        }
    }

    // ---- global max over the 64x64 tile -------------------------------
    float mx = row2[0].x;
    #pragma unroll
    for (int i = 0; i < 32; ++i) { mx = fmaxf(mx, row2[i].x); mx = fmaxf(mx, row2[i].y); }
    #pragma unroll
    for (int w = 1; w <= 32; w <<= 1)
        mx = fmaxf(mx, __shfl_xor(mx, w, 64));

    // ---- x0 row copy: exp(scaled - mx) --------------------------------
    #pragma unroll
    for (int i = 0; i < 32; ++i) {
        row2[i].x = __expf(__fsub_rn(row2[i].x, mx));
        row2[i].y = __expf(__fsub_rn(row2[i].y, mx));
    }

    // ---- x0 column copy: coalesced global re-read, identical op seq ---
    float col[64];
    #pragma unroll
    for (int i = 0; i < 64; ++i) {
        float raw = base[i * 64 + lane];
        col[i] = __expf(__fsub_rn(__fmul_rn(raw, invT), mx));
    }

    // ---- sinkhorn in diag(u) * X0 * diag(v) form ----------------------
    // Broadcast of v (row phase) / u (col phase) via LDS: wave-uniform
    // ds_read_b128 is a hardware broadcast. Pairing and summation order
    // identical to R6: rs = (A0.x+A0.y)+(A1.x+A1.y).
    const float4* bu4 = (const float4*)bufU;
    const float4* bv4 = (const float4*)bufV;

    float u = 1.0f, v = 1.0f;
    for (int it = 0; it < 30; ++it) {
        // row phase: rs_i = row_i . v
        bufV[lane] = v;
        f2 A0 = {0.f, 0.f}, A1 = {0.f, 0.f};
        #pragma unroll
        for (int t = 0; t < 16; ++t) {
            float4 q = bv4[t];
            f2 qa = { q.x, q.y };
            f2 qb = { q.z, q.w };
            A0 = fma2(row2[2*t+0], qa, A0);
            A1 = fma2(row2[2*t+1], qb, A1);
        }
        float rs = __fadd_rn(__fadd_rn(A0.x, A0.y), __fadd_rn(A1.x, A1.y));
        u = u / __fadd_rn(__fmul_rn(u, rs), 1e-8f);   // IEEE divide

        // col phase: cs_j = col_j . u  (updated u broadcast)
        bufU[lane] = u;
        A0 = (f2){0.f, 0.f}; A1 = (f2){0.f, 0.f};
        #pragma unroll
        for (int t = 0; t < 16; ++t) {
            float4 q = bu4[t];
            f2 ca = { col[4*t+0], col[4*t+1] };
            f2 cb = { col[4*t+2], col[4*t+3] };
            f2 qa = { q.x, q.y };
            f2 qb = { q.z, q.w };
            A0 = fma2(ca, qa, A0);
            A1 = fma2(cb, qb, A1);
        }
        float cs = __fadd_rn(__fadd_rn(A0.x, A0.y), __fadd_rn(A1.x, A1.y));
        v = v / __fadd_rn(__fmul_rn(v, cs), 1e-8f);
    }

    // ---- final scores: s[i][j] = (x0[i][j] * u_i) * v_j ---------------
    // bufU still holds the final u (last written in iteration 29's row phase).
    #pragma unroll
    for (int t = 0; t < 16; ++t) {
        float4 q = bu4[t];
        col[4*t+0] = __fmul_rn(__fmul_rn(col[4*t+0], q.x), v);
        col[4*t+1] = __fmul_rn(__fmul_rn(col[4*t+1], q.y), v);
        col[4*t+2] = __fmul_rn(__fmul_rn(col[4*t+2], q.z), v);
        col[4*t+3] = __fmul_rn(__fmul_rn(col[4*t+3], q.w), v);
    }

    // ---- greedy unique argmax (R5 verbatim: top-2 + verified fallback) -
    unsigned long long rowmask = ~0ull;   // wave-uniform (SGPR pair)
    float gv[8]; int ga[8];
    #pragma unroll
    for (int g = 0; g < 8; ++g) RESCAN(g)

    int  mycol   = 0;
    bool done    = false;
    int  retired = 0;
    const float NEGINF = -__builtin_inff();

    while (retired < 64) {
        // per-lane best over 8 groups (ascending + strict '>' => min row on tie)
        float bv = gv[0]; int ba = ga[0];
        #pragma unroll
        for (int g2 = 1; g2 < 8; ++g2)
            if (gv[g2] > bv) { bv = gv[g2]; ba = ga[g2]; }
        float mybv = done ? NEGINF : bv;

        // wave-wide top-2 values (butterfly; disjoint-group merge each stage)
        float m1 = mybv, m2 = NEGINF;
        #pragma unroll
        for (int m = 1; m <= 32; m <<= 1) {
            float o1 = __shfl_xor(m1, m, 64);
            float o2 = __shfl_xor(m2, m, 64);
            float hi = fmaxf(m1, o1);
            float lo = fminf(m1, o1);
            m1 = hi;
            m2 = fmaxf(lo, fmaxf(m2, o2));
        }

        int r1, c1, r2 = -1, c2 = -1;
        bool two = false;
        unsigned long long t1 = __ballot(mybv == m1);   // wave-uniform
        bool fast1 = (__popcll(t1) == 1) && (m2 > NEGINF);

        if (fast1) {
            c1 = (int)__builtin_ctzll(t1);
            r1 = __builtin_amdgcn_readlane(ba, c1);
            unsigned long long t2 = __ballot(mybv == m2);
            if (__popcll(t2) == 1) {
                c2 = (int)__builtin_ctzll(t2);
                r2 = __builtin_amdgcn_readlane(ba, c2);
                two = (r2 != r1);
            }
        } else {
            // fallback: R2-verified u64-key single retirement
            unsigned flat = ((unsigned)ba << 6) | (unsigned)lane;   // r*64 + c
            unsigned long long key =
                ((unsigned long long)__float_as_uint(bv) << 12) | (4095u - flat);
            if (done) key = 0ull;
            #pragma unroll
            for (int m = 1; m <= 32; m <<= 1) {
                unsigned long long o = __shfl_xor(key, m, 64);
                if (o > key) key = o;
            }
            unsigned wflat = 4095u - (unsigned)(key & 4095ull);
            r1 = __builtin_amdgcn_readfirstlane((int)(wflat >> 6));
            c1 = (int)(wflat & 63u);
        }

        // retire (r1,c1) [and (r2,c2)]
        if (lane == r1) mycol = c1;
        if (lane == c1) done  = true;
        rowmask &= ~(1ull << r1);
        retired++;
        if (two) {
            if (lane == r2) mycol = c2;
            if (lane == c2) done  = true;
            rowmask &= ~(1ull << r2);
            retired++;
        }

        // rescan affected group(s); (r>>3) is wave-uniform
        RESCAN_SWITCH(r1 >> 3)
        if (two && ((r2 >> 3) != (r1 >> 3))) {
            RESCAN_SWITCH(r2 >> 3)
        }
    }

    // ---- write hard permutation row (lane i -> row i) -----------------
    float* orow = out + (size_t)b * 4096 + lane * 64;
    #pragma unroll
    for (int t = 0; t < 16; ++t) {
        float4 q;
        q.x = (4*t+0 == mycol) ? 1.0f : 0.0f;
        q.y = (4*t+1 == mycol) ? 1.0f : 0.0f;
        q.z = (4*t+2 == mycol) ? 1.0f : 0.0f;
        q.w = (4*t+3 == mycol) ? 1.0f : 0.0f;
        ((float4*)orow)[t] = q;
    }
}

extern "C" void kernel_launch(void* const* d_in, const int* in_sizes, int n_in,
                              void* d_out, int out_size, void* d_ws, size_t ws_size,
                              hipStream_t stream) {
    const float* logits = (const float*)d_in[0];
    const float* ptemp  = (const float*)d_in[1];
    float* out = (float*)d_out;
    const int B = in_sizes[0] / 4096;   // 64*64 elements per batch
    sinkhorn_perm_kernel<<<B, 64, 0, stream>>>(logits, ptemp, out);
}

// Round 2
// 179.681 us; speedup vs baseline: 1.2368x; 1.1910x over previous
//
#include <hip/hip_runtime.h>
#include <cstdint>
#include <cstddef>

// One wave (64 lanes) per batch (B=4096, N=K=64).
// R8 change vs R7 (verified 140 us dispatch, VALUBusy 47%): replace the
// sequential greedy loop (~35 rounds, each a 6-stage shfl_xor butterfly =
// 12 dependent ds_bpermute ops ~1000cy/round) with EXACT parallel mutual-max
// retirement: each round, every live row finds its best live column and every
// live column its best live row (in-register masked scans, strict '>' over
// ascending index = reference argsort(-s) stable tie order), then all pairs
// that are mutual best are retired simultaneously. Sequential greedy over a
// strict total order (value desc, flat asc) == iterated mutual-best
// retirement (a mutual cell can never be blocked by an earlier pick), so the
// result is exact. Expected ~6-9 rounds instead of ~35. Requires scores in
// BOTH layouts; row-layout scores reuse row2 with the identical (x0*u)*v
// expression tree as the col layout => bitwise-equal. Sinkhorn phase is R7
// verbatim (bitwise-identical scores).

typedef float f2 __attribute__((ext_vector_type(2)));

__device__ __forceinline__ f2 fma2(f2 a, f2 b, f2 c) {
#if defined(__has_builtin) && __has_builtin(__builtin_elementwise_fma)
    return __builtin_elementwise_fma(a, b, c);
#else
    f2 r; r.x = __builtin_fmaf(a.x, b.x, c.x); r.y = __builtin_fmaf(a.y, b.y, c.y);
    return r;
#endif
}

__global__ void __launch_bounds__(64)
__attribute__((amdgpu_waves_per_eu(1)))
sinkhorn_perm_kernel(const float* __restrict__ logits,
                     const float* __restrict__ ptemp,
                     float* __restrict__ out)
{
    __shared__ __attribute__((aligned(16))) float bufU[64];
    __shared__ __attribute__((aligned(16))) float bufV[64];

    const int b    = blockIdx.x;
    const int lane = threadIdx.x;
    const float* base = logits + (size_t)b * 4096;

    const float T    = ptemp[0] + 1e-6f;
    const float invT = 1.0f / T;          // IEEE divide (one-time)

    // ---- load row `lane`, scale by invT; pairs (4t,4t+1),(4t+2,4t+3) --
    f2 row2[32];
    {
        const float4* rp = (const float4*)(base + lane * 64);
        #pragma unroll
        for (int t = 0; t < 16; ++t) {
            float4 q = rp[t];
            row2[2*t+0].x = __fmul_rn(q.x, invT);
            row2[2*t+0].y = __fmul_rn(q.y, invT);
            row2[2*t+1].x = __fmul_rn(q.z, invT);
            row2[2*t+1].y = __fmul_rn(q.w, invT);
        }
    }

    // ---- global max over the 64x64 tile -------------------------------
    float mx = row2[0].x;
    #pragma unroll
    for (int i = 0; i < 32; ++i) { mx = fmaxf(mx, row2[i].x); mx = fmaxf(mx, row2[i].y); }
    #pragma unroll
    for (int w = 1; w <= 32; w <<= 1)
        mx = fmaxf(mx, __shfl_xor(mx, w, 64));

    // ---- x0 row copy: exp(scaled - mx) --------------------------------
    #pragma unroll
    for (int i = 0; i < 32; ++i) {
        row2[i].x = __expf(__fsub_rn(row2[i].x, mx));
        row2[i].y = __expf(__fsub_rn(row2[i].y, mx));
    }

    // ---- x0 column copy: coalesced global re-read, identical op seq ---
    float col[64];
    #pragma unroll
    for (int i = 0; i < 64; ++i) {
        float raw = base[i * 64 + lane];
        col[i] = __expf(__fsub_rn(__fmul_rn(raw, invT), mx));
    }

    // ---- sinkhorn in diag(u) * X0 * diag(v) form ----------------------
    // Broadcast of v (row phase) / u (col phase) via LDS: wave-uniform
    // ds_read_b128 is a hardware broadcast. Pairing and summation order
    // identical to R6/R7: rs = (A0.x+A0.y)+(A1.x+A1.y).
    const float4* bu4 = (const float4*)bufU;
    const float4* bv4 = (const float4*)bufV;

    float u = 1.0f, v = 1.0f;
    for (int it = 0; it < 30; ++it) {
        // row phase: rs_i = row_i . v
        bufV[lane] = v;
        f2 A0 = {0.f, 0.f}, A1 = {0.f, 0.f};
        #pragma unroll
        for (int t = 0; t < 16; ++t) {
            float4 q = bv4[t];
            f2 qa = { q.x, q.y };
            f2 qb = { q.z, q.w };
            A0 = fma2(row2[2*t+0], qa, A0);
            A1 = fma2(row2[2*t+1], qb, A1);
        }
        float rs = __fadd_rn(__fadd_rn(A0.x, A0.y), __fadd_rn(A1.x, A1.y));
        u = u / __fadd_rn(__fmul_rn(u, rs), 1e-8f);   // IEEE divide

        // col phase: cs_j = col_j . u  (updated u broadcast)
        bufU[lane] = u;
        A0 = (f2){0.f, 0.f}; A1 = (f2){0.f, 0.f};
        #pragma unroll
        for (int t = 0; t < 16; ++t) {
            float4 q = bu4[t];
            f2 ca = { col[4*t+0], col[4*t+1] };
            f2 cb = { col[4*t+2], col[4*t+3] };
            f2 qa = { q.x, q.y };
            f2 qb = { q.z, q.w };
            A0 = fma2(ca, qa, A0);
            A1 = fma2(cb, qb, A1);
        }
        float cs = __fadd_rn(__fadd_rn(A0.x, A0.y), __fadd_rn(A1.x, A1.y));
        v = v / __fadd_rn(__fmul_rn(v, cs), 1e-8f);
    }

    // ---- final scores in BOTH layouts: s[i][j] = (x0[i][j] * u_i) * v_j
    // col layout (lane = col j): col[i] = (x0c[i] * bufU[i]) * v_own
    // bufU holds final u (last written in iteration 29's col phase).
    #pragma unroll
    for (int t = 0; t < 16; ++t) {
        float4 q = bu4[t];
        col[4*t+0] = __fmul_rn(__fmul_rn(col[4*t+0], q.x), v);
        col[4*t+1] = __fmul_rn(__fmul_rn(col[4*t+1], q.y), v);
        col[4*t+2] = __fmul_rn(__fmul_rn(col[4*t+2], q.z), v);
        col[4*t+3] = __fmul_rn(__fmul_rn(col[4*t+3], q.w), v);
    }
    // row layout (lane = row i): row2[j] = (x0r[j] * u_own) * bufV[j].
    // Same (x0*u)*v tree on bitwise-equal x0 and the same u_i / v_j bits
    // (u_own is this lane's register; bufV[j] is lane j's v register) =>
    // row/col score copies are bitwise identical.
    bufV[lane] = v;   // final v (in-order DS within wave, no barrier needed)
    #pragma unroll
    for (int t = 0; t < 16; ++t) {
        float4 q = bv4[t];
        row2[2*t+0].x = __fmul_rn(__fmul_rn(row2[2*t+0].x, u), q.x);
        row2[2*t+0].y = __fmul_rn(__fmul_rn(row2[2*t+0].y, u), q.y);
        row2[2*t+1].x = __fmul_rn(__fmul_rn(row2[2*t+1].x, u), q.z);
        row2[2*t+1].y = __fmul_rn(__fmul_rn(row2[2*t+1].y, u), q.w);
    }

    // ---- greedy unique argmax: parallel mutual-max retirement ----------
    // Total order: value desc, flat index (r*64+c) asc — matches
    // jnp.argsort(-s) stable semantics. Masked scans use strict '>' over
    // ascending index => exact total-order argmax per row/col (all scores
    // are > 0, so masking to 0.0f never wins; bv init 0.0f).
    unsigned long long rowmask = ~0ull;   // wave-uniform (SGPR pair)
    unsigned long long colmask = ~0ull;
    int mycol  = 0;
    int rounds = 0;

    while (rowmask && rounds < 64) {
        ++rounds;

        // row side (lane = row i): best live column
        float rbv = 0.0f; int rbj = 0;
        #pragma unroll
        for (int j = 0; j < 64; ++j) {
            unsigned sm = ((colmask >> j) & 1ull) ? 0xFFFFFFFFu : 0u;
            float sv = (j & 1) ? row2[j >> 1].y : row2[j >> 1].x;
            float s  = __uint_as_float(__float_as_uint(sv) & sm);
            if (s > rbv) { rbv = s; rbj = j; }
        }

        // col side (lane = col j): best live row
        float cbv = 0.0f; int cbi = 0;
        #pragma unroll
        for (int i = 0; i < 64; ++i) {
            unsigned sm = ((rowmask >> i) & 1ull) ? 0xFFFFFFFFu : 0u;
            float s  = __uint_as_float(__float_as_uint(col[i]) & sm);
            if (s > cbv) { cbv = s; cbi = i; }
        }

        // mutual check: row i's candidate col c=rbj is mutual iff
        // colArg[c] == i; col j's candidate row r=cbi is mutual iff
        // rowArg[r] == j. (Candidates from masked scans are always live.)
        int gr = __builtin_amdgcn_ds_bpermute(rbj << 2, cbi); // colArg[rbj]
        int gc = __builtin_amdgcn_ds_bpermute(cbi << 2, rbj); // rowArg[cbi]
        bool aR = (rowmask >> lane) & 1ull;
        bool aC = (colmask >> lane) & 1ull;
        bool mr = aR && (gr == lane);
        bool mc = aC && (gc == lane);
        if (mr) mycol = rbj;
        rowmask &= ~__ballot(mr);
        colmask &= ~__ballot(mc);
    }

    // ---- write hard permutation row (lane i -> row i) -----------------
    float* orow = out + (size_t)b * 4096 + lane * 64;
    #pragma unroll
    for (int t = 0; t < 16; ++t) {
        float4 q;
        q.x = (4*t+0 == mycol) ? 1.0f : 0.0f;
        q.y = (4*t+1 == mycol) ? 1.0f : 0.0f;
        q.z = (4*t+2 == mycol) ? 1.0f : 0.0f;
        q.w = (4*t+3 == mycol) ? 1.0f : 0.0f;
        ((float4*)orow)[t] = q;
    }
}

extern "C" void kernel_launch(void* const* d_in, const int* in_sizes, int n_in,
                              void* d_out, int out_size, void* d_ws, size_t ws_size,
                              hipStream_t stream) {
    const float* logits = (const float*)d_in[0];
    const float* ptemp  = (const float*)d_in[1];
    float* out = (float*)d_out;
    const int B = in_sizes[0] / 4096;   // 64*64 elements per batch
    sinkhorn_perm_kernel<<<B, 64, 0, stream>>>(logits, ptemp, out);
}